// Round 1
// baseline (421.032 us; speedup 1.0000x reference)
//
#include <hip/hip_runtime.h>
#include <math.h>

#define KN 1024      // oscillators
#define KB 128       // batch
#define KDT 0.1f
#define KSTEPS 10
#define KM2 256      // 2*KB rows: [0,128)=sin(theta[b]), [128,256)=cos(theta[b])

// X^T layout: xt[j*KM2 + m], j = oscillator index (reduction dim), m = stacked row.

__global__ __launch_bounds__(256)
void k_init(const float* __restrict__ theta0, float* __restrict__ xt)
{
    int tid = blockIdx.x * 256 + threadIdx.x;   // 0..131071
    int b = tid & (KB - 1);
    int j = tid >> 7;
    float t = theta0[(size_t)b * KN + j];
    float s = sinf(t), c = cosf(t);
    xt[(size_t)j * KM2 + b] = s;
    xt[(size_t)j * KM2 + KB + b] = c;
}

// Fused GEMM + Euler update + wrap + next-step sincos.
// Grid: 256 blocks = (g in {0,1} batch-half) x (128 i-tiles of 8 columns).
// Block: 512 threads = 128 local rows x 4 j-quarters.
__global__ __launch_bounds__(512)
void k_step(const float* __restrict__ xt_in,
            float* __restrict__ xt_out,
            const float* __restrict__ theta_in,
            float* __restrict__ theta_out,
            const float* __restrict__ Kmat,
            const float* __restrict__ omega,
            const float* __restrict__ kg)
{
    const int g  = blockIdx.x >> 7;        // batch half
    const int it = blockIdx.x & 127;       // i-tile
    const int i0 = it * 8;

    const int tid = threadIdx.x;           // 0..511
    const int ml  = tid & 127;             // local row
    const int q   = tid >> 7;              // j-quarter

    // global stacked-row index: sin rows m=b, cos rows m=128+b, b = g*64 + (ml%64)
    const int mg = (ml < 64) ? (g * 64 + ml) : (64 + g * 64 + ml);

    float acc[8];
    #pragma unroll
    for (int c = 0; c < 8; ++c) acc[c] = 0.0f;

    const float* xp = xt_in + (size_t)(q * 256) * KM2 + mg;
    const float* kp = Kmat + (size_t)(q * 256) * KN + i0;   // K[j][i0..i0+7], symmetric K

    #pragma unroll 4
    for (int jj = 0; jj < 256; ++jj) {
        float x = xp[(size_t)jj * KM2];
        const float4 k0 = *reinterpret_cast<const float4*>(kp + (size_t)jj * KN);
        const float4 k1 = *reinterpret_cast<const float4*>(kp + (size_t)jj * KN + 4);
        acc[0] = fmaf(x, k0.x, acc[0]);
        acc[1] = fmaf(x, k0.y, acc[1]);
        acc[2] = fmaf(x, k0.z, acc[2]);
        acc[3] = fmaf(x, k0.w, acc[3]);
        acc[4] = fmaf(x, k1.x, acc[4]);
        acc[5] = fmaf(x, k1.y, acc[5]);
        acc[6] = fmaf(x, k1.z, acc[6]);
        acc[7] = fmaf(x, k1.w, acc[7]);
    }

    __shared__ float red[3][128][8];   // 12 KB: quarters 1..3 partials
    __shared__ float ysum[128][8];     // 4 KB: reduced sums

    if (q > 0) {
        #pragma unroll
        for (int c = 0; c < 8; ++c) red[q - 1][ml][c] = acc[c];
    }
    __syncthreads();
    if (q == 0) {
        #pragma unroll
        for (int c = 0; c < 8; ++c)
            ysum[ml][c] = acc[c] + red[0][ml][c] + red[1][ml][c] + red[2][ml][c];
    }
    __syncthreads();

    // Update: 64 batches x 8 columns = 512 elements, one per thread.
    {
        const int bl = tid & 63;
        const int c  = tid >> 6;            // 0..7
        const int b  = g * 64 + bl;
        const int i  = i0 + c;
        const float Ys = ysum[bl][c];       // sin-row sum (local ml = bl)
        const float Yc = ysum[64 + bl][c];  // cos-row sum (local ml = 64+bl)
        const float sn = xt_in[(size_t)i * KM2 + b];        // sin(theta[b][i])
        const float cs = xt_in[(size_t)i * KM2 + KB + b];   // cos(theta[b][i])
        const float th = theta_in[(size_t)b * KN + i];
        const float scale = kg[0] * (1.0f / (float)KN);
        const float coupling = cs * Ys - sn * Yc;
        float tn = th + KDT * (omega[i] + scale * coupling);
        // wrap to (-pi, pi] exactly like arctan2(sin, cos)
        float s2 = sinf(tn), c2 = cosf(tn);
        float tw = atan2f(s2, c2);
        theta_out[(size_t)b * KN + i] = tw;
        // next step's sincos computed on the wrapped value (matches reference)
        float s3 = sinf(tw), c3 = cosf(tw);
        xt_out[(size_t)i * KM2 + b] = s3;
        xt_out[(size_t)i * KM2 + KB + b] = c3;
    }
}

__global__ __launch_bounds__(256)
void k_coh(const float* __restrict__ theta, float* __restrict__ out_coh)
{
    const int b = blockIdx.x;       // 0..127
    const int t = threadIdx.x;      // 0..255
    float ssum = 0.0f, csum = 0.0f;
    #pragma unroll
    for (int k = 0; k < 4; ++k) {
        float th = theta[(size_t)b * KN + t + k * 256];
        ssum += sinf(th);
        csum += cosf(th);
    }
    __shared__ float rs[256], rc[256];
    rs[t] = ssum; rc[t] = csum;
    __syncthreads();
    for (int off = 128; off > 0; off >>= 1) {
        if (t < off) { rs[t] += rs[t + off]; rc[t] += rc[t + off]; }
        __syncthreads();
    }
    if (t == 0) {
        float cm = rc[0] * (1.0f / (float)KN);
        float sm = rs[0] * (1.0f / (float)KN);
        out_coh[b] = sqrtf(cm * cm + sm * sm);
    }
}

extern "C" void kernel_launch(void* const* d_in, const int* in_sizes, int n_in,
                              void* d_out, int out_size, void* d_ws, size_t ws_size,
                              hipStream_t stream)
{
    (void)in_sizes; (void)n_in; (void)out_size; (void)ws_size;

    const float* theta0 = (const float*)d_in[0];
    const float* Kmat   = (const float*)d_in[1];
    const float* omega  = (const float*)d_in[2];
    const float* kg     = (const float*)d_in[3];

    float* out_theta = (float*)d_out;              // 128*1024 floats
    float* out_coh   = out_theta + (size_t)KB * KN; // +128 floats

    float* xtA = (float*)d_ws;                     // 1 MB each
    float* xtB = xtA + (size_t)KN * KM2;

    k_init<<<512, 256, 0, stream>>>(theta0, xtA);

    const float* th_in = theta0;
    float* xin = xtA;
    float* xout = xtB;
    for (int s = 0; s < KSTEPS; ++s) {
        k_step<<<256, 512, 0, stream>>>(xin, xout, th_in, out_theta, Kmat, omega, kg);
        th_in = out_theta;
        float* tmp = xin; xin = xout; xout = tmp;
    }

    k_coh<<<KB, 256, 0, stream>>>(out_theta, out_coh);
}

// Round 2
// 247.648 us; speedup vs baseline: 1.7001x; 1.7001x over previous
//
#include <hip/hip_runtime.h>
#include <math.h>

#define KN 1024
#define KB 128
#define KDT 0.1f
#define KSTEPS 10

typedef __attribute__((ext_vector_type(8))) short short8;
typedef __attribute__((ext_vector_type(4))) float floatx4;

__device__ __forceinline__ unsigned short f2bf(float f) {
    unsigned u = __float_as_uint(f);
    u += 0x7FFF + ((u >> 16) & 1);          // round-to-nearest-even
    return (unsigned short)(u >> 16);
}
__device__ __forceinline__ float bf2f(unsigned short h) {
    return __uint_as_float(((unsigned)h) << 16);
}

// K fp32 -> bf16 hi + lo (runs every launch; K is symmetric so Kb rows serve
// as MFMA B-operand columns with contiguous-k loads).
__global__ __launch_bounds__(256)
void k_prep(const float* __restrict__ K,
            unsigned short* __restrict__ kh,
            unsigned short* __restrict__ kl)
{
    int e = blockIdx.x * 256 + threadIdx.x;     // 0 .. 1048575
    float v = K[e];
    unsigned short h = f2bf(v);
    kh[e] = h;
    kl[e] = f2bf(v - bf2f(h));
}

// theta0 -> X (rows [0,128)=sin, [128,256)=cos), bf16 hi+lo, [m][j] row-major.
__global__ __launch_bounds__(256)
void k_init(const float* __restrict__ theta0,
            unsigned short* __restrict__ xh,
            unsigned short* __restrict__ xl)
{
    int e = blockIdx.x * 256 + threadIdx.x;     // 0 .. 131071
    int b = e >> 10, j = e & 1023;
    float t = theta0[e];
    float s = sinf(t), c = cosf(t);
    unsigned short sh = f2bf(s);
    unsigned short ch = f2bf(c);
    xh[(size_t)b * KN + j]              = sh;
    xl[(size_t)b * KN + j]              = f2bf(s - bf2f(sh));
    xh[(size_t)(KB + b) * KN + j]       = ch;
    xl[(size_t)(KB + b) * KN + j]       = f2bf(c - bf2f(ch));
}

// Fused: Y = X*K via MFMA (split bf16), Euler update, wrap, next X (bf16 split).
// Grid: 256 blocks = 8 b-chunks(16) x 32 i-chunks(32). Block: 256 thr = 4 waves.
// Wave w: wm=w&1 (0=sin rows b0.., 1=cos rows 128+b0..), wi=w>>1 (i-sub of 16).
__global__ __launch_bounds__(256)
void k_step(const unsigned short* __restrict__ xh_in,
            const unsigned short* __restrict__ xl_in,
            unsigned short* __restrict__ xh_out,
            unsigned short* __restrict__ xl_out,
            const float* __restrict__ theta_in,
            float* __restrict__ theta_out,
            const unsigned short* __restrict__ kbh,
            const unsigned short* __restrict__ kbl,
            const float* __restrict__ omega,
            const float* __restrict__ kg)
{
    const int b0 = (blockIdx.x >> 5) * 16;      // batch chunk
    const int i0 = (blockIdx.x & 31) * 32;      // column chunk

    const int tid  = threadIdx.x;
    const int lane = tid & 63;
    const int wave = tid >> 6;
    const int wm   = wave & 1;                  // 0: sin rows, 1: cos rows
    const int wi   = wave >> 1;                 // i sub-tile

    const int r16  = lane & 15;
    const int quad = lane >> 4;

    // A: X[m][k], m = (wm?128:0)+b0+r16, k = kk + quad*8 .. +7 (16B contiguous)
    const unsigned short* aH = xh_in + (size_t)((wm ? KB : 0) + b0 + r16) * KN + quad * 8;
    const unsigned short* aL = xl_in + (size_t)((wm ? KB : 0) + b0 + r16) * KN + quad * 8;
    // B: Kb[i][k] (symmetric K => B[k][n=i]), i = i0 + wi*16 + r16
    const unsigned short* bH = kbh + (size_t)(i0 + wi * 16 + r16) * KN + quad * 8;
    const unsigned short* bL = kbl + (size_t)(i0 + wi * 16 + r16) * KN + quad * 8;

    floatx4 acc0 = {0.f, 0.f, 0.f, 0.f};
    floatx4 acc1 = {0.f, 0.f, 0.f, 0.f};

    #pragma unroll 4
    for (int kk = 0; kk < KN; kk += 32) {
        short8 ah = *(const short8*)(aH + kk);
        short8 al = *(const short8*)(aL + kk);
        short8 bh = *(const short8*)(bH + kk);
        short8 bl = *(const short8*)(bL + kk);
        acc0 = __builtin_amdgcn_mfma_f32_16x16x32_bf16(ah, bh, acc0, 0, 0, 0);
        acc1 = __builtin_amdgcn_mfma_f32_16x16x32_bf16(ah, bl, acc1, 0, 0, 0);
        acc1 = __builtin_amdgcn_mfma_f32_16x16x32_bf16(al, bh, acc1, 0, 0, 0);
    }

    // C/D layout: lane,reg -> D[m = quad*4+reg][n = lane&15]
    __shared__ float ldsY[2][16][33];           // [wm][m_local][i_local], +1 pad
    {
        const int il = wi * 16 + r16;
        #pragma unroll
        for (int r = 0; r < 4; ++r)
            ldsY[wm][quad * 4 + r][il] = acc0[r] + acc1[r];
    }
    __syncthreads();

    // Update: 16 b x 32 i = 512 elems, 2 per thread.
    const float scale = kg[0] * (1.0f / (float)KN);
    #pragma unroll
    for (int p = 0; p < 2; ++p) {
        const int e  = tid + p * 256;
        const int bl_ = e >> 5;                 // 0..15
        const int il  = e & 31;                 // 0..31
        const int b   = b0 + bl_;
        const int i   = i0 + il;
        const float Ys = ldsY[0][bl_][il];
        const float Yc = ldsY[1][bl_][il];
        const float th = theta_in[(size_t)b * KN + i];
        float sn, cs;
        __sincosf(th, &sn, &cs);                // fp32-accurate sin/cos of theta
        const float coupling = cs * Ys - sn * Yc;
        float tn = th + KDT * (omega[i] + scale * coupling);
        float s2 = sinf(tn), c2 = cosf(tn);
        float tw = atan2f(s2, c2);              // wrap to (-pi, pi]
        theta_out[(size_t)b * KN + i] = tw;
        // next-step X = sin/cos of wrapped theta == (s2, c2) to ~1 ulp
        unsigned short sh = f2bf(s2);
        unsigned short ch = f2bf(c2);
        xh_out[(size_t)b * KN + i]        = sh;
        xl_out[(size_t)b * KN + i]        = f2bf(s2 - bf2f(sh));
        xh_out[(size_t)(KB + b) * KN + i] = ch;
        xl_out[(size_t)(KB + b) * KN + i] = f2bf(c2 - bf2f(ch));
    }
}

__global__ __launch_bounds__(256)
void k_coh(const float* __restrict__ theta, float* __restrict__ out_coh)
{
    const int b = blockIdx.x;
    const int t = threadIdx.x;
    float ssum = 0.0f, csum = 0.0f;
    #pragma unroll
    for (int k = 0; k < 4; ++k) {
        float th = theta[(size_t)b * KN + t + k * 256];
        float s, c;
        __sincosf(th, &s, &c);
        ssum += s; csum += c;
    }
    __shared__ float rs[256], rc[256];
    rs[t] = ssum; rc[t] = csum;
    __syncthreads();
    for (int off = 128; off > 0; off >>= 1) {
        if (t < off) { rs[t] += rs[t + off]; rc[t] += rc[t + off]; }
        __syncthreads();
    }
    if (t == 0) {
        float cm = rc[0] * (1.0f / (float)KN);
        float sm = rs[0] * (1.0f / (float)KN);
        out_coh[b] = sqrtf(cm * cm + sm * sm);
    }
}

extern "C" void kernel_launch(void* const* d_in, const int* in_sizes, int n_in,
                              void* d_out, int out_size, void* d_ws, size_t ws_size,
                              hipStream_t stream)
{
    (void)in_sizes; (void)n_in; (void)out_size; (void)ws_size;

    const float* theta0 = (const float*)d_in[0];
    const float* Kmat   = (const float*)d_in[1];
    const float* omega  = (const float*)d_in[2];
    const float* kg     = (const float*)d_in[3];

    float* out_theta = (float*)d_out;                    // 128*1024 f32
    float* out_coh   = out_theta + (size_t)KB * KN;      // +128 f32

    // Workspace layout (bytes):
    //   [0, 2M)   Kb_hi   [2M, 4M) Kb_lo
    //   [4M..)    X ping-pong: xhA, xlA, xhB, xlB (512 KB each)
    unsigned short* kbh = (unsigned short*)d_ws;
    unsigned short* kbl = kbh + (size_t)KN * KN;
    unsigned short* xhA = kbl + (size_t)KN * KN;
    unsigned short* xlA = xhA + (size_t)2 * KB * KN;
    unsigned short* xhB = xlA + (size_t)2 * KB * KN;
    unsigned short* xlB = xhB + (size_t)2 * KB * KN;

    k_prep<<<(KN * KN) / 256, 256, 0, stream>>>(Kmat, kbh, kbl);
    k_init<<<(KB * KN) / 256, 256, 0, stream>>>(theta0, xhA, xlA);

    const float* th_in = theta0;
    unsigned short *xh_in = xhA, *xl_in = xlA, *xh_out = xhB, *xl_out = xlB;
    for (int s = 0; s < KSTEPS; ++s) {
        k_step<<<256, 256, 0, stream>>>(xh_in, xl_in, xh_out, xl_out,
                                        th_in, out_theta, kbh, kbl, omega, kg);
        th_in = out_theta;
        unsigned short* t1 = xh_in; xh_in = xh_out; xh_out = t1;
        unsigned short* t2 = xl_in; xl_in = xl_out; xl_out = t2;
    }

    k_coh<<<KB, 256, 0, stream>>>(out_theta, out_coh);
}

// Round 3
// 145.885 us; speedup vs baseline: 2.8861x; 1.6976x over previous
//
#include <hip/hip_runtime.h>
#include <math.h>

#define KN 1024
#define KB 128
#define KDT 0.1f
#define KSTEPS 10

typedef __attribute__((ext_vector_type(8))) short short8;
typedef __attribute__((ext_vector_type(4))) float floatx4;

__device__ __forceinline__ unsigned short f2bf(float f) {
    unsigned u = __float_as_uint(f);
    u += 0x7FFF + ((u >> 16) & 1);          // round-to-nearest-even
    return (unsigned short)(u >> 16);
}

// K fp32 -> bf16 (hi only), 4 elems/thread. K symmetric => rows double as
// MFMA B-operand columns with contiguous-k loads.
__global__ __launch_bounds__(256)
void k_prep(const float* __restrict__ K, unsigned short* __restrict__ kh)
{
    int e4 = blockIdx.x * 256 + threadIdx.x;        // 0..262143
    const float4 v = reinterpret_cast<const float4*>(K)[e4];
    ushort4 h;
    h.x = f2bf(v.x); h.y = f2bf(v.y); h.z = f2bf(v.z); h.w = f2bf(v.w);
    reinterpret_cast<ushort4*>(kh)[e4] = h;
}

// theta0 -> X bf16: rows [0,128)=sin(theta[b]), [128,256)=cos(theta[b]).
__global__ __launch_bounds__(256)
void k_init(const float* __restrict__ theta0, unsigned short* __restrict__ xh)
{
    int e = blockIdx.x * 256 + threadIdx.x;         // 0..131071
    int b = e >> 10, j = e & 1023;
    float t = theta0[e];
    float s, c;
    __sincosf(t, &s, &c);
    xh[(size_t)b * KN + j]        = f2bf(s);
    xh[(size_t)(KB + b) * KN + j] = f2bf(c);
}

// Fused: Y = X*K (bf16 MFMA), Euler update, wrap, next-step X.
// Grid 256 = 8 b-chunks(16) x 32 i-chunks(32). Block 1024 thr = 16 waves.
// Wave: wi = i-subtile (2 x 16 cols), kq = K-eighth (128 k each).
// Each wave computes BOTH sin and cos C-tiles sharing one B fragment.
__global__ __launch_bounds__(1024)
void k_step(const unsigned short* __restrict__ xh_in,
            unsigned short* __restrict__ xh_out,
            const float* __restrict__ theta_in,
            float* __restrict__ theta_out,
            const unsigned short* __restrict__ kbh,
            const float* __restrict__ omega,
            const float* __restrict__ kg)
{
    const int b0 = (blockIdx.x >> 5) * 16;
    const int i0 = (blockIdx.x & 31) * 32;

    const int tid  = threadIdx.x;
    const int lane = tid & 63;
    const int wave = tid >> 6;          // 0..15
    const int wi   = wave & 1;
    const int kq   = wave >> 1;         // 0..7
    const int r16  = lane & 15;
    const int quad = lane >> 4;

    const int kbase = kq * 128 + quad * 8;

    // A fragments: A[m=lane&15][k=quad*8+j]; sin rows b0+r16, cos rows KB+b0+r16
    const unsigned short* aS = xh_in + (size_t)(b0 + r16) * KN + kbase;
    const unsigned short* aC = xh_in + (size_t)(KB + b0 + r16) * KN + kbase;
    // B fragment: B[k][n=lane&15] = Kb[i0+wi*16+r16][k] (K symmetric)
    const unsigned short* bP = kbh + (size_t)(i0 + wi * 16 + r16) * KN + kbase;

    floatx4 accS = {0.f, 0.f, 0.f, 0.f};
    floatx4 accC = {0.f, 0.f, 0.f, 0.f};

    #pragma unroll
    for (int kk = 0; kk < 128; kk += 32) {
        short8 a_s = *(const short8*)(aS + kk);
        short8 a_c = *(const short8*)(aC + kk);
        short8 b_  = *(const short8*)(bP + kk);
        accS = __builtin_amdgcn_mfma_f32_16x16x32_bf16(a_s, b_, accS, 0, 0, 0);
        accC = __builtin_amdgcn_mfma_f32_16x16x32_bf16(a_c, b_, accC, 0, 0, 0);
    }

    // C/D layout: D[m = quad*4+reg][n = lane&15]
    __shared__ float ldsY[8][2][16][34];   // [kq][sin/cos][m][i_local+pad] ~34.8 KB
    const int il = wi * 16 + r16;
    #pragma unroll
    for (int r = 0; r < 4; ++r) {
        ldsY[kq][0][quad * 4 + r][il] = accS[r];
        ldsY[kq][1][quad * 4 + r][il] = accC[r];
    }
    __syncthreads();

    // Update: 16 b x 32 i = 512 elems on first 512 threads.
    if (tid < 512) {
        const int bl_ = tid >> 5;          // 0..15
        const int ilo = tid & 31;          // 0..31
        float Ys = 0.f, Yc = 0.f;
        #pragma unroll
        for (int q = 0; q < 8; ++q) {
            Ys += ldsY[q][0][bl_][ilo];
            Yc += ldsY[q][1][bl_][ilo];
        }
        const int b = b0 + bl_;
        const int i = i0 + ilo;
        const float th = theta_in[(size_t)b * KN + i];
        float sn, cs;
        __sincosf(th, &sn, &cs);
        const float scale = kg[0] * (1.0f / (float)KN);
        const float coupling = cs * Ys - sn * Yc;
        float tn = th + KDT * (omega[i] + scale * coupling);
        float s2 = __sinf(tn), c2 = __cosf(tn);
        float tw = atan2f(s2, c2);         // wrap to (-pi, pi], matches reference
        theta_out[(size_t)b * KN + i] = tw;
        // next-step X = sin/cos of wrapped theta == (s2, c2) up to 2*pi shift
        xh_out[(size_t)b * KN + i]        = f2bf(s2);
        xh_out[(size_t)(KB + b) * KN + i] = f2bf(c2);
    }
}

__global__ __launch_bounds__(256)
void k_coh(const float* __restrict__ theta, float* __restrict__ out_coh)
{
    const int b = blockIdx.x;
    const int t = threadIdx.x;
    float ssum = 0.0f, csum = 0.0f;
    #pragma unroll
    for (int k = 0; k < 4; ++k) {
        float th = theta[(size_t)b * KN + t + k * 256];
        float s, c;
        __sincosf(th, &s, &c);
        ssum += s; csum += c;
    }
    __shared__ float rs[256], rc[256];
    rs[t] = ssum; rc[t] = csum;
    __syncthreads();
    for (int off = 128; off > 0; off >>= 1) {
        if (t < off) { rs[t] += rs[t + off]; rc[t] += rc[t + off]; }
        __syncthreads();
    }
    if (t == 0) {
        float cm = rc[0] * (1.0f / (float)KN);
        float sm = rs[0] * (1.0f / (float)KN);
        out_coh[b] = sqrtf(cm * cm + sm * sm);
    }
}

extern "C" void kernel_launch(void* const* d_in, const int* in_sizes, int n_in,
                              void* d_out, int out_size, void* d_ws, size_t ws_size,
                              hipStream_t stream)
{
    (void)in_sizes; (void)n_in; (void)out_size; (void)ws_size;

    const float* theta0 = (const float*)d_in[0];
    const float* Kmat   = (const float*)d_in[1];
    const float* omega  = (const float*)d_in[2];
    const float* kg     = (const float*)d_in[3];

    float* out_theta = (float*)d_out;                    // 128*1024 f32
    float* out_coh   = out_theta + (size_t)KB * KN;      // +128 f32

    // Workspace: Kb (2 MB) + X ping-pong (512 KB each)
    unsigned short* kbh = (unsigned short*)d_ws;
    unsigned short* xhA = kbh + (size_t)KN * KN;
    unsigned short* xhB = xhA + (size_t)2 * KB * KN;

    k_prep<<<(KN * KN) / 4 / 256, 256, 0, stream>>>(Kmat, kbh);
    k_init<<<(KB * KN) / 256, 256, 0, stream>>>(theta0, xhA);

    const float* th_in = theta0;
    unsigned short *xin = xhA, *xout = xhB;
    for (int s = 0; s < KSTEPS; ++s) {
        k_step<<<256, 1024, 0, stream>>>(xin, xout, th_in, out_theta,
                                         kbh, omega, kg);
        th_in = out_theta;
        unsigned short* t1 = xin; xin = xout; xout = t1;
    }

    k_coh<<<KB, 256, 0, stream>>>(out_theta, out_coh);
}